// Round 6
// baseline (157.610 us; speedup 1.0000x reference)
//
#include <hip/hip_runtime.h>

// Shapes: x [n=32, c=32, s=1, h=48, w=48]; hw = 2304; c*s = 32.
// energy = q k^T is rank-1  =>  out[n,i,:] = gamma * f(q_i) + x, where
// f_d(t) = sum_j e^{t k_j} v_r[j,d] / sum_j e^{t k_j}.
// f is smooth in 1 variable -> 64-node Chebyshev barycentric interpolation
// on the exact per-batch q-range (error orders below the 9.9e-2 threshold).
//
// v (9.4 MB) is staged in d_out: prep writes it, fnode reads it ONCE
// (j-chunk-major loop nest), eval overwrites all of d_out with the result.
#define NB 32
#define CC 32
#define HW 2304
#define RN 64                     // Chebyshev nodes per batch
#define JCHUNK 256                // j rows per fnode block (9 chunks = HW)
#define LOG2E 1.4426950408889634f
#define PI_F  3.14159265358979323846f

// Workspace layout (float offsets). Total = 141888 floats = 554 KB.
#define OFF_POOL 0u          // pool[n][hw]            73728
#define OFF_PART 73728u      // min/max partials       288*2 = 576
#define OFF_F    74304u      // F[n][r][32] unnormalized  65536 (atomic accum)
#define OFF_Z    139840u     // Z[n][r]                2048   (atomic accum)
#define ZERO_CNT 67584u      // F+Z zero-init span (adjacent)

__device__ __forceinline__ float frcp(float v) { return __builtin_amdgcn_rcpf(v); }

// ---------------------------------------------------------------------------
// Kernel 1: pool = mean_c + max_c (store); v = Wv@x + bv (1x1 conv) -> vout;
// per-block pool min/max partials; zero-init F/Z accumulators.
// grid (9, 32), block 256: thread = one spatial position p.
// ---------------------------------------------------------------------------
__global__ __launch_bounds__(256) void prep_kernel(
    const float* __restrict__ x,
    const float* __restrict__ Wv, const float* __restrict__ bv,
    float* __restrict__ vout,      // = d_out used as scratch for v[n][c][hw]
    float* __restrict__ ws)
{
    __shared__ float smin[256], smax[256];
    const int tid = threadIdx.x;
    const int n   = blockIdx.y;
    const int p   = blockIdx.x * 256 + tid;

    // zero-init the atomic accumulators (F then Z, adjacent region)
    {
        const unsigned g = (blockIdx.y * 9u + blockIdx.x) * 256u + tid;
        if (g < ZERO_CNT) ws[OFF_F + g] = 0.0f;
    }

    const float* xb = x + (size_t)n * (CC * HW) + p;
    float xx[CC];
    float sum = 0.f, mx = -3.0e38f;
#pragma unroll
    for (int c = 0; c < CC; ++c) {
        float v = xb[(size_t)c * HW];   // coalesced across threads
        xx[c] = v;
        sum += v;
        mx = fmaxf(mx, v);
    }
    const float pool = sum * (1.0f / CC) + mx;
    ws[OFF_POOL + n * HW + p] = pool;

    // channel-mix: Wv indices are uniform -> scalar loads
    float* vb = vout + (size_t)n * (CC * HW) + p;
#pragma unroll 8
    for (int o = 0; o < CC; ++o) {
        float acc = bv[o];
#pragma unroll
        for (int c = 0; c < CC; ++c) acc = fmaf(Wv[o * CC + c], xx[c], acc);
        vb[(size_t)o * HW] = acc;       // coalesced across threads
    }

    // block-level pool min/max
    smin[tid] = pool; smax[tid] = pool;
    __syncthreads();
    for (int s = 128; s > 0; s >>= 1) {
        if (tid < s) {
            smin[tid] = fminf(smin[tid], smin[tid + s]);
            smax[tid] = fmaxf(smax[tid], smax[tid + s]);
        }
        __syncthreads();
    }
    if (tid == 0) {
        const int b = n * gridDim.x + blockIdx.x;
        ws[OFF_PART + 2 * b]     = smin[0];
        ws[OFF_PART + 2 * b + 1] = smax[0];
    }
}

// ---------------------------------------------------------------------------
// Kernel 2: F[n][r][d] += sum_{j in chunk} e^{t_r k_j - m_r} v_r[j,d];
//           Z[n][r]    += sum_{j in chunk} e^{t_r k_j - m_r}.
// j-chunk-major: each block reads its 32 KB v slice ONCE into LDS; every
// thread owns (r = tid&63, d-octet = tid>>6) and accumulates in registers.
// LDS reads are wave-broadcast (same jj, same octet) -> zero bank conflicts.
// grid (9, 32), block 256.
// ---------------------------------------------------------------------------
__global__ __launch_bounds__(256) void fnode_kernel(
    const float* __restrict__ Wq, const float* __restrict__ bq,
    const float* __restrict__ Wk, const float* __restrict__ bk,
    const float* __restrict__ vscratch,
    float* __restrict__ ws)
{
    __shared__ __align__(16) float sv[JCHUNK * 32];   // 32 KB
    __shared__ float sk[JCHUNK];
    const int tid = threadIdx.x;
    const int n   = blockIdx.y;
    const int jb  = blockIdx.x * JCHUNK;

    // stage v slice (contiguous: v_r[j][d] == vflat[j*32+d]) and k chunk
    const float* vsrc = vscratch + (size_t)n * (CC * HW) + (size_t)jb * 32;
    for (int idx = tid; idx < JCHUNK * 32; idx += 256)
        sv[idx] = vsrc[idx];
    const float Wk0 = Wk[0], bk0 = bk[0];
    sk[tid] = fmaf(Wk0, ws[OFF_POOL + n * HW + jb + tid], bk0);

    // per-lane node params (r distinct per lane within a wave)
    const int r    = tid & 63;
    const int dblk = tid >> 6;            // 0..3 -> d octet
    float pmin = 3.0e38f, pmax = -3.0e38f;
#pragma unroll
    for (int b = 0; b < 9; ++b) {
        pmin = fminf(pmin, ws[OFF_PART + 2 * (n * 9 + b)]);
        pmax = fmaxf(pmax, ws[OFF_PART + 2 * (n * 9 + b) + 1]);
    }
    const float q1 = fmaf(Wq[0], pmin, bq[0]);
    const float q2 = fmaf(Wq[0], pmax, bq[0]);
    const float qlo = fminf(q1, q2), qhi = fmaxf(q1, q2);
    const float k1 = fmaf(Wk0, pmin, bk0);
    const float k2 = fmaf(Wk0, pmax, bk0);
    const float klo = fminf(k1, k2), khi = fmaxf(k1, k2);
    const float mid  = 0.5f * (qlo + qhi);
    const float half = fmaxf(0.5f * (qhi - qlo), 1e-6f);
    const float t  = fmaf(half, cosf(PI_F * (float)r / (float)(RN - 1)), mid);
    const float m  = fmaxf(t * klo, t * khi);   // == max_j t*k_j (k range exact)
    const float tl = t * LOG2E;
    const float ml = m * LOG2E;

    __syncthreads();

    float a0 = 0.f, a1 = 0.f, a2 = 0.f, a3 = 0.f;
    float a4 = 0.f, a5 = 0.f, a6 = 0.f, a7 = 0.f, az = 0.f;
    const float* svd = sv + dblk * 8;
#pragma unroll 4
    for (int jj = 0; jj < JCHUNK; ++jj) {
        const float e = exp2f(fmaf(tl, sk[jj], -ml));   // exponent <= 0
        const float4 va = *(const float4*)(svd + jj * 32);       // broadcast
        const float4 vb = *(const float4*)(svd + jj * 32 + 4);   // broadcast
        a0 = fmaf(e, va.x, a0); a1 = fmaf(e, va.y, a1);
        a2 = fmaf(e, va.z, a2); a3 = fmaf(e, va.w, a3);
        a4 = fmaf(e, vb.x, a4); a5 = fmaf(e, vb.y, a5);
        a6 = fmaf(e, vb.z, a6); a7 = fmaf(e, vb.w, a7);
        az += e;
    }

    float* Fb = ws + OFF_F + ((size_t)n * RN + r) * 32 + dblk * 8;
    atomicAdd(Fb + 0, a0); atomicAdd(Fb + 1, a1);
    atomicAdd(Fb + 2, a2); atomicAdd(Fb + 3, a3);
    atomicAdd(Fb + 4, a4); atomicAdd(Fb + 5, a5);
    atomicAdd(Fb + 6, a6); atomicAdd(Fb + 7, a7);
    if (dblk == 0) atomicAdd(ws + OFF_Z + n * RN + r, az);
}

// ---------------------------------------------------------------------------
// Kernel 3: barycentric evaluation at each q_i + residual epilogue.
// Overwrites ALL of d_out (which held v scratch).
// grid (72, 32), block 256: 8 threads per i (4 d's each) -> coalesced float4 IO.
// ---------------------------------------------------------------------------
__global__ __launch_bounds__(256) void eval_kernel(
    const float* __restrict__ x,
    const float* __restrict__ Wq, const float* __restrict__ bq,
    const float* __restrict__ gamma,
    const float* __restrict__ ws,
    float* __restrict__ out)
{
    __shared__ __align__(16) float sF[RN * 32];
    __shared__ float stn[RN];
    __shared__ float sstat[2];
    const int tid = threadIdx.x;
    const int n   = blockIdx.y;

    if (tid == 0) {
        float pmin = 3.0e38f, pmax = -3.0e38f;
        for (int b = 0; b < 9; ++b) {
            pmin = fminf(pmin, ws[OFF_PART + 2 * (n * 9 + b)]);
            pmax = fmaxf(pmax, ws[OFF_PART + 2 * (n * 9 + b) + 1]);
        }
        sstat[0] = pmin; sstat[1] = pmax;
    }
    // stage F normalized by Z
    const float* Fb = ws + OFF_F + (size_t)n * RN * 32;
    const float* Zb = ws + OFF_Z + (size_t)n * RN;
    for (int idx = tid; idx < RN * 32; idx += 256)
        sF[idx] = Fb[idx] / Zb[idx >> 5];
    __syncthreads();
    if (tid < RN) {
        const float pmin = sstat[0], pmax = sstat[1];
        const float q1 = fmaf(Wq[0], pmin, bq[0]);
        const float q2 = fmaf(Wq[0], pmax, bq[0]);
        const float qlo = fminf(q1, q2), qhi = fmaxf(q1, q2);
        const float mid  = 0.5f * (qlo + qhi);
        const float half = fmaxf(0.5f * (qhi - qlo), 1e-6f);
        stn[tid] = fmaf(half, cosf(PI_F * (float)tid / (float)(RN - 1)), mid);
    }
    __syncthreads();

    const int il = tid >> 3;                 // 32 i's per block
    const int dg = tid & 7;                  // 4-wide d group
    const int i  = blockIdx.x * 32 + il;
    const float t = fmaf(Wq[0], ws[OFF_POOL + n * HW + i], bq[0]);  // q_i

    // Barycentric Lagrange, Chebyshev-2 weights (-1)^r * (1/2 at ends).
    float n0 = 0.f, n1 = 0.f, n2 = 0.f, n3 = 0.f, den = 0.f;
    float sgn = 1.0f;
#pragma unroll 8
    for (int r = 0; r < RN; ++r) {
        float d = t - stn[r];
        if (fabsf(d) < 1e-20f) d = 1e-20f;   // node-hit guard
        const float lam = (r == 0 || r == RN - 1) ? 0.5f : 1.0f;
        const float w = sgn * lam * frcp(d);
        sgn = -sgn;
        den += w;
        const float4 f4 = *(const float4*)(&sF[r * 32 + dg * 4]);
        n0 = fmaf(w, f4.x, n0);
        n1 = fmaf(w, f4.y, n1);
        n2 = fmaf(w, f4.z, n2);
        n3 = fmaf(w, f4.w, n3);
    }
    const float invden = frcp(den);
    const float g = gamma[0];
    const int c_out = i / 72;
    const int p_out = (i - c_out * 72) * 32 + dg * 4;
    const size_t base = (size_t)n * (CC * HW) + (size_t)c_out * HW + p_out;
    const float4 xv = *(const float4*)(x + base);
    float4 o;
    o.x = fmaf(g, n0 * invden, xv.x);
    o.y = fmaf(g, n1 * invden, xv.y);
    o.z = fmaf(g, n2 * invden, xv.z);
    o.w = fmaf(g, n3 * invden, xv.w);
    *(float4*)(out + base) = o;
}

extern "C" void kernel_launch(void* const* d_in, const int* in_sizes, int n_in,
                              void* d_out, int out_size, void* d_ws, size_t ws_size,
                              hipStream_t stream) {
    const float* x     = (const float*)d_in[0];
    const float* Wq    = (const float*)d_in[1];
    const float* bq    = (const float*)d_in[2];
    const float* Wk    = (const float*)d_in[3];
    const float* bk    = (const float*)d_in[4];
    const float* Wv    = (const float*)d_in[5];
    const float* bv    = (const float*)d_in[6];
    const float* gamma = (const float*)d_in[7];
    float* out = (float*)d_out;
    float* ws  = (float*)d_ws;   // needs only 554 KB

    // v is staged in d_out (overwritten by eval with the final result).
    prep_kernel<<<dim3(9, NB), 256, 0, stream>>>(x, Wv, bv, out, ws);
    fnode_kernel<<<dim3(9, NB), 256, 0, stream>>>(Wq, bq, Wk, bk, out, ws);
    eval_kernel<<<dim3(72, NB), 256, 0, stream>>>(x, Wq, bq, gamma, ws, out);
}

// Round 10
// 141.866 us; speedup vs baseline: 1.1110x; 1.1110x over previous
//
#include <hip/hip_runtime.h>

// Shapes: x [n=32, c=32, s=1, h=48, w=48]; hw = 2304; c*s = 32.
// energy = q k^T is rank-1  =>  out[n,i,:] = gamma * f(q_i) + x, where
// f_d(t) = sum_j e^{t k_j} v_r[j,d] / sum_j e^{t k_j}.
// f is smooth in 1 variable -> 64-node Chebyshev barycentric interpolation
// on the exact per-batch q-range (error orders below the 9.9e-2 threshold).
// v (9.4 MB) staged in d_out (prep writes, fnode reads once, eval overwrites).
//
// R6 post-mortem: fnode was latency-bound at 1.1 waves/SIMD (288 blocks,
// 256-iter serial chains). This version: 256 fnode blocks x 16 waves
// (1 block/CU exactly, 72-iter loops), 1152 prep blocks (256-FMA chains).
#define NB 32
#define CC 32
#define HW 2304
#define RN 64                     // Chebyshev nodes per batch
#define PCHUNK 64                 // positions per prep block
#define NPB 36                    // prep blocks per batch  (HW/PCHUNK)
#define JCHUNK 288                // j rows per fnode block
#define NFB 8                     // fnode blocks per batch (HW/JCHUNK)
#define LOG2E 1.4426950408889634f
#define PI_F  3.14159265358979323846f

// Workspace layout (float offsets). Total = 143616 floats = 574 KB.
#define OFF_POOL 0u          // pool[n][hw]            73728
#define OFF_PART 73728u      // min/max partials       1152*2 = 2304
#define OFF_F    76032u      // F[n][r][32] unnormalized  65536 (atomic accum)
#define OFF_Z    141568u     // Z[n][r]                2048   (atomic accum)
#define ZERO_CNT 67584u      // F+Z zero-init span (adjacent)

__device__ __forceinline__ float frcp(float v) { return __builtin_amdgcn_rcpf(v); }

// ---------------------------------------------------------------------------
// Kernel 1: pool = mean_c + max_c (store); v = Wv@x + bv (1x1 conv) -> vout;
// per-block pool min/max partials; zero-init F/Z accumulators.
// grid (36, 32), block 256: 64 positions/block, 4 threads per position
// (each computes 8 output channels). x tile + Wv^T staged in LDS.
// ---------------------------------------------------------------------------
__global__ __launch_bounds__(256) void prep_kernel(
    const float* __restrict__ x,
    const float* __restrict__ Wv, const float* __restrict__ bv,
    float* __restrict__ vout,      // = d_out used as scratch for v[n][c][hw]
    float* __restrict__ ws)
{
    __shared__ float sx[CC][PCHUNK];        // 8 KB   x tile, c-major
    __shared__ __align__(16) float sWvT[CC][36];  // transposed Wv, pad->16B-aligned rows
    __shared__ float sbv[CC];
    const int tid = threadIdx.x;
    const int n   = blockIdx.y;
    const int pb  = blockIdx.x * PCHUNK;

    // zero-init the atomic accumulators (F then Z, adjacent region)
    {
        const unsigned g = (blockIdx.y * NPB + blockIdx.x) * 256u + tid;
        if (g < ZERO_CNT) ws[OFF_F + g] = 0.0f;
    }

    if (tid < CC) sbv[tid] = bv[tid];
    for (int idx = tid; idx < CC * CC; idx += 256) {
        const int o = idx >> 5, c = idx & 31;
        sWvT[c][o] = Wv[idx];               // Wv row-major [o][c]
    }
    const float* xb = x + (size_t)n * (CC * HW) + pb;
    for (int idx = tid; idx < CC * PCHUNK; idx += 256) {
        const int c = idx >> 6, p = idx & 63;
        sx[c][p] = xb[(size_t)c * HW + p];  // coalesced 256B per wave
    }
    __syncthreads();

    const int pos = tid & 63;
    const int og  = tid >> 6;               // 0..3 -> 8 output channels each

    float acc[8];
#pragma unroll
    for (int oo = 0; oo < 8; ++oo) acc[oo] = sbv[og * 8 + oo];
#pragma unroll
    for (int c = 0; c < CC; ++c) {
        const float xv = sx[c][pos];        // 2 lanes/bank, conflict-free
        const float4 w0 = *(const float4*)&sWvT[c][og * 8];      // broadcast
        const float4 w1 = *(const float4*)&sWvT[c][og * 8 + 4];  // broadcast
        acc[0] = fmaf(w0.x, xv, acc[0]); acc[1] = fmaf(w0.y, xv, acc[1]);
        acc[2] = fmaf(w0.z, xv, acc[2]); acc[3] = fmaf(w0.w, xv, acc[3]);
        acc[4] = fmaf(w1.x, xv, acc[4]); acc[5] = fmaf(w1.y, xv, acc[5]);
        acc[6] = fmaf(w1.z, xv, acc[6]); acc[7] = fmaf(w1.w, xv, acc[7]);
    }
    float* vb = vout + (size_t)n * (CC * HW) + pb + pos;
#pragma unroll
    for (int oo = 0; oo < 8; ++oo)
        vb[(size_t)(og * 8 + oo) * HW] = acc[oo];   // coalesced 256B per wave

    // pooling: wave 0 (og==0), one thread per position
    if (og == 0) {
        float sum = 0.f, mx = -3.0e38f;
#pragma unroll
        for (int c = 0; c < CC; ++c) {
            const float v = sx[c][pos];
            sum += v;
            mx = fmaxf(mx, v);
        }
        const float pool = sum * (1.0f / CC) + mx;
        ws[OFF_POOL + n * HW + pb + pos] = pool;
        float mn = pool, mxp = pool;
#pragma unroll
        for (int off = 32; off > 0; off >>= 1) {
            mn  = fminf(mn,  __shfl_xor(mn,  off));
            mxp = fmaxf(mxp, __shfl_xor(mxp, off));
        }
        if (tid == 0) {
            const int b = n * NPB + blockIdx.x;
            ws[OFF_PART + 2 * b]     = mn;
            ws[OFF_PART + 2 * b + 1] = mxp;
        }
    }
}

// ---------------------------------------------------------------------------
// Kernel 2: F[n][r][d] += sum_{j in chunk} e^{t_r k_j - m_r} v_r[j,d];  Z too.
// grid (8, 32) = 256 blocks (exactly 1/CU), block 1024 (16 waves).
// thread = (r = tid&63, dblk = (tid>>6)&3, jh = tid>>8): 72-iter j loop,
// 4-way jh partials merged via LDS (sv reused, pad-9), then atomics.
// ---------------------------------------------------------------------------
__global__ __launch_bounds__(1024) void fnode_kernel(
    const float* __restrict__ Wq, const float* __restrict__ bq,
    const float* __restrict__ Wk, const float* __restrict__ bk,
    const float* __restrict__ vscratch,
    float* __restrict__ ws)
{
    __shared__ __align__(16) float sv[JCHUNK * 32];   // 36 KB (reused as reduce scratch)
    __shared__ float sk[JCHUNK];
    __shared__ float sz[1024];
    const int tid = threadIdx.x;
    const int n   = blockIdx.y;
    const int jb  = blockIdx.x * JCHUNK;

    // stage v slice (contiguous: v_r[j][d] == vflat[j*32+d]) and k chunk
    const float* vsrc = vscratch + (size_t)n * (CC * HW) + (size_t)jb * 32;
    for (int idx = tid; idx < JCHUNK * 32; idx += 1024)
        sv[idx] = vsrc[idx];
    const float Wk0 = Wk[0], bk0 = bk[0];
    for (int idx = tid; idx < JCHUNK; idx += 1024)
        sk[idx] = fmaf(Wk0, ws[OFF_POOL + n * HW + jb + idx], bk0);

    const int r    = tid & 63;
    const int dblk = (tid >> 6) & 3;
    const int jh   = tid >> 8;            // 0..3
    float pmin = 3.0e38f, pmax = -3.0e38f;
    for (int b = 0; b < NPB; ++b) {       // uniform -> s_loads
        pmin = fminf(pmin, ws[OFF_PART + 2 * (n * NPB + b)]);
        pmax = fmaxf(pmax, ws[OFF_PART + 2 * (n * NPB + b) + 1]);
    }
    const float q1 = fmaf(Wq[0], pmin, bq[0]);
    const float q2 = fmaf(Wq[0], pmax, bq[0]);
    const float qlo = fminf(q1, q2), qhi = fmaxf(q1, q2);
    const float k1 = fmaf(Wk0, pmin, bk0);
    const float k2 = fmaf(Wk0, pmax, bk0);
    const float klo = fminf(k1, k2), khi = fmaxf(k1, k2);
    const float mid  = 0.5f * (qlo + qhi);
    const float half = fmaxf(0.5f * (qhi - qlo), 1e-6f);
    const float t  = fmaf(half, cosf(PI_F * (float)r / (float)(RN - 1)), mid);
    const float m  = fmaxf(t * klo, t * khi);   // == max_j t*k_j (k range exact)
    const float tl = t * LOG2E;
    const float ml = m * LOG2E;

    __syncthreads();

    float a0 = 0.f, a1 = 0.f, a2 = 0.f, a3 = 0.f;
    float a4 = 0.f, a5 = 0.f, a6 = 0.f, a7 = 0.f, az = 0.f;
    const float* svd = sv + dblk * 8;
    const int j0 = jh * 72;
#pragma unroll 4
    for (int jj = j0; jj < j0 + 72; ++jj) {
        const float e = exp2f(fmaf(tl, sk[jj], -ml));   // exponent <= 0
        const float4 va = *(const float4*)(svd + jj * 32);       // broadcast
        const float4 vb = *(const float4*)(svd + jj * 32 + 4);   // broadcast
        a0 = fmaf(e, va.x, a0); a1 = fmaf(e, va.y, a1);
        a2 = fmaf(e, va.z, a2); a3 = fmaf(e, va.w, a3);
        a4 = fmaf(e, vb.x, a4); a5 = fmaf(e, vb.y, a5);
        a6 = fmaf(e, vb.z, a6); a7 = fmaf(e, vb.w, a7);
        az += e;
    }

    __syncthreads();                // sv no longer needed as v; reuse for reduce
    // partial store: sred[jh][lid][9-pad], lid = dblk*64 + r = tid&255
    const int lid = tid & 255;
    float* sred = sv;               // 4 * 256 * 9 = 9216 floats fits sv
    {
        float* dst = sred + (jh * 256 + lid) * 9;
        dst[0] = a0; dst[1] = a1; dst[2] = a2; dst[3] = a3;
        dst[4] = a4; dst[5] = a5; dst[6] = a6; dst[7] = a7;
    }
    sz[tid] = az;
    __syncthreads();
    if (tid < 256) {
        const int rr = lid & 63, db = lid >> 6;
        float* Fb = ws + OFF_F + ((size_t)n * RN + rr) * 32 + db * 8;
#pragma unroll
        for (int dd = 0; dd < 8; ++dd) {
            const float s = sred[(0 * 256 + lid) * 9 + dd]
                          + sred[(1 * 256 + lid) * 9 + dd]
                          + sred[(2 * 256 + lid) * 9 + dd]
                          + sred[(3 * 256 + lid) * 9 + dd];
            atomicAdd(Fb + dd, s);
        }
        if (db == 0) {
            const float z = sz[rr] + sz[256 + rr] + sz[512 + rr] + sz[768 + rr];
            atomicAdd(ws + OFF_Z + n * RN + rr, z);
        }
    }
}

// ---------------------------------------------------------------------------
// Kernel 3: barycentric evaluation at each q_i + residual epilogue.
// Overwrites ALL of d_out (which held v scratch).
// grid (72, 32), block 256: 8 threads per i (4 d's each) -> coalesced float4 IO.
// ---------------------------------------------------------------------------
__global__ __launch_bounds__(256) void eval_kernel(
    const float* __restrict__ x,
    const float* __restrict__ Wq, const float* __restrict__ bq,
    const float* __restrict__ gamma,
    const float* __restrict__ ws,
    float* __restrict__ out)
{
    __shared__ __align__(16) float sF[RN * 32];
    __shared__ float stn[RN];
    __shared__ float sstat[2];
    const int tid = threadIdx.x;
    const int n   = blockIdx.y;

    if (tid == 0) {
        float pmin = 3.0e38f, pmax = -3.0e38f;
        for (int b = 0; b < NPB; ++b) {
            pmin = fminf(pmin, ws[OFF_PART + 2 * (n * NPB + b)]);
            pmax = fmaxf(pmax, ws[OFF_PART + 2 * (n * NPB + b) + 1]);
        }
        sstat[0] = pmin; sstat[1] = pmax;
    }
    // stage F normalized by Z
    const float* Fb = ws + OFF_F + (size_t)n * RN * 32;
    const float* Zb = ws + OFF_Z + (size_t)n * RN;
    for (int idx = tid; idx < RN * 32; idx += 256)
        sF[idx] = Fb[idx] / Zb[idx >> 5];
    __syncthreads();
    if (tid < RN) {
        const float pmin = sstat[0], pmax = sstat[1];
        const float q1 = fmaf(Wq[0], pmin, bq[0]);
        const float q2 = fmaf(Wq[0], pmax, bq[0]);
        const float qlo = fminf(q1, q2), qhi = fmaxf(q1, q2);
        const float mid  = 0.5f * (qlo + qhi);
        const float half = fmaxf(0.5f * (qhi - qlo), 1e-6f);
        stn[tid] = fmaf(half, cosf(PI_F * (float)tid / (float)(RN - 1)), mid);
    }
    __syncthreads();

    const int il = tid >> 3;                 // 32 i's per block
    const int dg = tid & 7;                  // 4-wide d group
    const int i  = blockIdx.x * 32 + il;
    const float t = fmaf(Wq[0], ws[OFF_POOL + n * HW + i], bq[0]);  // q_i

    // Barycentric Lagrange, Chebyshev-2 weights (-1)^r * (1/2 at ends).
    float n0 = 0.f, n1 = 0.f, n2 = 0.f, n3 = 0.f, den = 0.f;
    float sgn = 1.0f;
#pragma unroll 8
    for (int r = 0; r < RN; ++r) {
        float d = t - stn[r];
        if (fabsf(d) < 1e-20f) d = 1e-20f;   // node-hit guard
        const float lam = (r == 0 || r == RN - 1) ? 0.5f : 1.0f;
        const float w = sgn * lam * frcp(d);
        sgn = -sgn;
        den += w;
        const float4 f4 = *(const float4*)(&sF[r * 32 + dg * 4]);
        n0 = fmaf(w, f4.x, n0);
        n1 = fmaf(w, f4.y, n1);
        n2 = fmaf(w, f4.z, n2);
        n3 = fmaf(w, f4.w, n3);
    }
    const float invden = frcp(den);
    const float g = gamma[0];
    const int c_out = i / 72;
    const int p_out = (i - c_out * 72) * 32 + dg * 4;
    const size_t base = (size_t)n * (CC * HW) + (size_t)c_out * HW + p_out;
    const float4 xv = *(const float4*)(x + base);
    float4 o;
    o.x = fmaf(g, n0 * invden, xv.x);
    o.y = fmaf(g, n1 * invden, xv.y);
    o.z = fmaf(g, n2 * invden, xv.z);
    o.w = fmaf(g, n3 * invden, xv.w);
    *(float4*)(out + base) = o;
}

extern "C" void kernel_launch(void* const* d_in, const int* in_sizes, int n_in,
                              void* d_out, int out_size, void* d_ws, size_t ws_size,
                              hipStream_t stream) {
    const float* x     = (const float*)d_in[0];
    const float* Wq    = (const float*)d_in[1];
    const float* bq    = (const float*)d_in[2];
    const float* Wk    = (const float*)d_in[3];
    const float* bk    = (const float*)d_in[4];
    const float* Wv    = (const float*)d_in[5];
    const float* bv    = (const float*)d_in[6];
    const float* gamma = (const float*)d_in[7];
    float* out = (float*)d_out;
    float* ws  = (float*)d_ws;   // needs only 574 KB

    // v is staged in d_out (overwritten by eval with the final result).
    prep_kernel<<<dim3(NPB, NB), 256, 0, stream>>>(x, Wv, bv, out, ws);
    fnode_kernel<<<dim3(NFB, NB), 1024, 0, stream>>>(Wq, bq, Wk, bk, out, ws);
    eval_kernel<<<dim3(72, NB), 256, 0, stream>>>(x, Wq, bq, gamma, ws, out);
}

// Round 11
// 122.173 us; speedup vs baseline: 1.2901x; 1.1612x over previous
//
#include <hip/hip_runtime.h>

// Shapes: x [n=32, c=32, s=1, h=48, w=48]; hw = 2304; c*s = 32.
// energy = q k^T is rank-1  =>  out[n,i,:] = gamma * f(q_i) + x, where
// f_d(t) = sum_j e^{t k_j} v_r[j,d] / sum_j e^{t k_j}.
// f is smooth in 1 variable -> 64-node Chebyshev barycentric interpolation
// on the exact per-batch q-range. v (9.4 MB) staged in d_out.
//
// R10 post-mortem: fnode was atomic-bound (524K cross-XCD fp32 RMWs, 43.5us,
// occupancy 18% = 4-wave merge tail). This version: NO atomics — per-block
// partial tiles stored coalesced; eval sums the 8 partials during staging.
#define NB 32
#define CC 32
#define HW 2304
#define RN 64                     // Chebyshev nodes per batch
#define PCHUNK 64                 // positions per prep block
#define NPB 36                    // prep blocks per batch  (HW/PCHUNK)
#define JCHUNK 288                // j rows per fnode block
#define NFB 8                     // fnode blocks per batch (HW/JCHUNK)
#define LOG2E 1.4426950408889634f
#define PI_F  3.14159265358979323846f

// Workspace layout (float offsets). Total = 616704 floats = 2.4 MB.
#define OFF_POOL 0u          // pool[n][hw]              73728
#define OFF_PART 73728u      // min/max partials         1152*2 = 2304
#define OFF_FP   76032u      // F partials [n][blk][r*32+d]  32*8*2048 = 524288
#define OFF_ZP   600320u     // Z partials [n][blk][r]       32*8*64   = 16384

__device__ __forceinline__ float frcp(float v) { return __builtin_amdgcn_rcpf(v); }

// ---------------------------------------------------------------------------
// Kernel 1: pool = mean_c + max_c (store); v = Wv@x + bv (1x1 conv) -> vout;
// per-block pool min/max partials.
// grid (36, 32), block 256: 64 positions/block, 4 threads per position
// (each computes 8 output channels). x tile + Wv^T staged in LDS.
// ---------------------------------------------------------------------------
__global__ __launch_bounds__(256) void prep_kernel(
    const float* __restrict__ x,
    const float* __restrict__ Wv, const float* __restrict__ bv,
    float* __restrict__ vout,      // = d_out used as scratch for v[n][c][hw]
    float* __restrict__ ws)
{
    __shared__ float sx[CC][PCHUNK];        // 8 KB   x tile, c-major
    __shared__ __align__(16) float sWvT[CC][36];  // transposed Wv, padded rows
    __shared__ float sbv[CC];
    const int tid = threadIdx.x;
    const int n   = blockIdx.y;
    const int pb  = blockIdx.x * PCHUNK;

    if (tid < CC) sbv[tid] = bv[tid];
    for (int idx = tid; idx < CC * CC; idx += 256) {
        const int o = idx >> 5, c = idx & 31;
        sWvT[c][o] = Wv[idx];               // Wv row-major [o][c]
    }
    const float* xb = x + (size_t)n * (CC * HW) + pb;
    for (int idx = tid; idx < CC * PCHUNK; idx += 256) {
        const int c = idx >> 6, p = idx & 63;
        sx[c][p] = xb[(size_t)c * HW + p];  // coalesced 256B per wave
    }
    __syncthreads();

    const int pos = tid & 63;
    const int og  = tid >> 6;               // 0..3 -> 8 output channels each

    float acc[8];
#pragma unroll
    for (int oo = 0; oo < 8; ++oo) acc[oo] = sbv[og * 8 + oo];
#pragma unroll
    for (int c = 0; c < CC; ++c) {
        const float xv = sx[c][pos];        // 2 lanes/bank, conflict-free
        const float4 w0 = *(const float4*)&sWvT[c][og * 8];      // broadcast
        const float4 w1 = *(const float4*)&sWvT[c][og * 8 + 4];  // broadcast
        acc[0] = fmaf(w0.x, xv, acc[0]); acc[1] = fmaf(w0.y, xv, acc[1]);
        acc[2] = fmaf(w0.z, xv, acc[2]); acc[3] = fmaf(w0.w, xv, acc[3]);
        acc[4] = fmaf(w1.x, xv, acc[4]); acc[5] = fmaf(w1.y, xv, acc[5]);
        acc[6] = fmaf(w1.z, xv, acc[6]); acc[7] = fmaf(w1.w, xv, acc[7]);
    }
    float* vb = vout + (size_t)n * (CC * HW) + pb + pos;
#pragma unroll
    for (int oo = 0; oo < 8; ++oo)
        vb[(size_t)(og * 8 + oo) * HW] = acc[oo];   // coalesced 256B per wave

    // pooling: wave 0 (og==0), one thread per position
    if (og == 0) {
        float sum = 0.f, mx = -3.0e38f;
#pragma unroll
        for (int c = 0; c < CC; ++c) {
            const float v = sx[c][pos];
            sum += v;
            mx = fmaxf(mx, v);
        }
        const float pool = sum * (1.0f / CC) + mx;
        ws[OFF_POOL + n * HW + pb + pos] = pool;
        float mn = pool, mxp = pool;
#pragma unroll
        for (int off = 32; off > 0; off >>= 1) {
            mn  = fminf(mn,  __shfl_xor(mn,  off));
            mxp = fmaxf(mxp, __shfl_xor(mxp, off));
        }
        if (tid == 0) {
            const int b = n * NPB + blockIdx.x;
            ws[OFF_PART + 2 * b]     = mn;
            ws[OFF_PART + 2 * b + 1] = mxp;
        }
    }
}

// ---------------------------------------------------------------------------
// Kernel 2: per-block PARTIAL F/Z (no atomics):
//   FP[n][blk][r][d] = sum_{j in chunk} e^{t_r k_j - m_r} v_r[j,d]
//   ZP[n][blk][r]    = sum_{j in chunk} e^{t_r k_j - m_r}
// grid (8, 32) = 256 blocks, block 1024 (16 waves).
// thread = (r = tid&63, dblk = (tid>>6)&3, jh = tid>>8): 72-iter j loop,
// 4-way jh partials merged via LDS (sv reused, pad-9), coalesced stores.
// ---------------------------------------------------------------------------
__global__ __launch_bounds__(1024) void fnode_kernel(
    const float* __restrict__ Wq, const float* __restrict__ bq,
    const float* __restrict__ Wk, const float* __restrict__ bk,
    const float* __restrict__ vscratch,
    float* __restrict__ ws)
{
    __shared__ __align__(16) float sv[JCHUNK * 32];   // 36 KB (reused as reduce scratch)
    __shared__ float sk[JCHUNK];
    __shared__ float sz[1024];
    const int tid = threadIdx.x;
    const int n   = blockIdx.y;
    const int bx  = blockIdx.x;
    const int jb  = bx * JCHUNK;

    // stage v slice (contiguous: v_r[j][d] == vflat[j*32+d]) and k chunk
    const float* vsrc = vscratch + (size_t)n * (CC * HW) + (size_t)jb * 32;
    for (int idx = tid; idx < JCHUNK * 32; idx += 1024)
        sv[idx] = vsrc[idx];
    const float Wk0 = Wk[0], bk0 = bk[0];
    for (int idx = tid; idx < JCHUNK; idx += 1024)
        sk[idx] = fmaf(Wk0, ws[OFF_POOL + n * HW + jb + idx], bk0);

    const int r    = tid & 63;
    const int dblk = (tid >> 6) & 3;
    const int jh   = tid >> 8;            // 0..3
    float pmin = 3.0e38f, pmax = -3.0e38f;
    for (int b = 0; b < NPB; ++b) {       // uniform -> s_loads
        pmin = fminf(pmin, ws[OFF_PART + 2 * (n * NPB + b)]);
        pmax = fmaxf(pmax, ws[OFF_PART + 2 * (n * NPB + b) + 1]);
    }
    const float q1 = fmaf(Wq[0], pmin, bq[0]);
    const float q2 = fmaf(Wq[0], pmax, bq[0]);
    const float qlo = fminf(q1, q2), qhi = fmaxf(q1, q2);
    const float k1 = fmaf(Wk0, pmin, bk0);
    const float k2 = fmaf(Wk0, pmax, bk0);
    const float klo = fminf(k1, k2), khi = fmaxf(k1, k2);
    const float mid  = 0.5f * (qlo + qhi);
    const float half = fmaxf(0.5f * (qhi - qlo), 1e-6f);
    const float t  = fmaf(half, cosf(PI_F * (float)r / (float)(RN - 1)), mid);
    const float m  = fmaxf(t * klo, t * khi);   // == max_j t*k_j (k range exact)
    const float tl = t * LOG2E;
    const float ml = m * LOG2E;

    __syncthreads();

    float a0 = 0.f, a1 = 0.f, a2 = 0.f, a3 = 0.f;
    float a4 = 0.f, a5 = 0.f, a6 = 0.f, a7 = 0.f, az = 0.f;
    const float* svd = sv + dblk * 8;
    const int j0 = jh * 72;
#pragma unroll 4
    for (int jj = j0; jj < j0 + 72; ++jj) {
        const float e = exp2f(fmaf(tl, sk[jj], -ml));   // exponent <= 0
        const float4 va = *(const float4*)(svd + jj * 32);       // broadcast
        const float4 vb = *(const float4*)(svd + jj * 32 + 4);   // broadcast
        a0 = fmaf(e, va.x, a0); a1 = fmaf(e, va.y, a1);
        a2 = fmaf(e, va.z, a2); a3 = fmaf(e, va.w, a3);
        a4 = fmaf(e, vb.x, a4); a5 = fmaf(e, vb.y, a5);
        a6 = fmaf(e, vb.z, a6); a7 = fmaf(e, vb.w, a7);
        az += e;
    }

    __syncthreads();                // sv no longer needed as v; reuse for reduce
    // partial store: sred[jh][lid][9-pad], lid = dblk*64 + r = tid&255
    const int lid = tid & 255;
    float* sred = sv;               // 4 * 256 * 9 = 9216 floats fits sv
    {
        float* dst = sred + (jh * 256 + lid) * 9;
        dst[0] = a0; dst[1] = a1; dst[2] = a2; dst[3] = a3;
        dst[4] = a4; dst[5] = a5; dst[6] = a6; dst[7] = a7;
    }
    sz[tid] = az;
    __syncthreads();
    if (tid < 256) {
        // remapped so stores are contiguous: thread -> (rr = tid>>2, db = tid&3)
        const int rr = tid >> 2, db = tid & 3;
        float s[8];
#pragma unroll
        for (int dd = 0; dd < 8; ++dd) {
            s[dd] = sred[(0 * 256 + db * 64 + rr) * 9 + dd]
                  + sred[(1 * 256 + db * 64 + rr) * 9 + dd]
                  + sred[(2 * 256 + db * 64 + rr) * 9 + dd]
                  + sred[(3 * 256 + db * 64 + rr) * 9 + dd];
        }
        // FP addr = (n*NFB+bx)*2048 + rr*32 + db*8 = ... + tid*8  (contiguous)
        float* Fb = ws + OFF_FP + ((size_t)(n * NFB + bx)) * (RN * 32) + tid * 8;
        *(float4*)(Fb)     = make_float4(s[0], s[1], s[2], s[3]);
        *(float4*)(Fb + 4) = make_float4(s[4], s[5], s[6], s[7]);
        if (db == 0) {
            const float z = sz[rr] + sz[256 + rr] + sz[512 + rr] + sz[768 + rr];
            ws[OFF_ZP + (n * NFB + bx) * RN + rr] = z;
        }
    }
}

// ---------------------------------------------------------------------------
// Kernel 3: sum the 8 F/Z partials while staging, then barycentric evaluation
// at each q_i + residual epilogue. Overwrites ALL of d_out (held v scratch).
// grid (72, 32), block 256: 8 threads per i (4 d's each) -> coalesced IO.
// ---------------------------------------------------------------------------
__global__ __launch_bounds__(256) void eval_kernel(
    const float* __restrict__ x,
    const float* __restrict__ Wq, const float* __restrict__ bq,
    const float* __restrict__ gamma,
    const float* __restrict__ ws,
    float* __restrict__ out)
{
    __shared__ __align__(16) float sF[RN * 32];
    __shared__ float stn[RN];
    __shared__ float sZ2[RN];
    __shared__ float sstat[2];
    const int tid = threadIdx.x;
    const int n   = blockIdx.y;

    if (tid == 0) {
        float pmin = 3.0e38f, pmax = -3.0e38f;
        for (int b = 0; b < NPB; ++b) {
            pmin = fminf(pmin, ws[OFF_PART + 2 * (n * NPB + b)]);
            pmax = fmaxf(pmax, ws[OFF_PART + 2 * (n * NPB + b) + 1]);
        }
        sstat[0] = pmin; sstat[1] = pmax;
    }
    if (tid < RN) {   // Z = sum of 8 partials
        float zz = 0.f;
#pragma unroll
        for (int b = 0; b < NFB; ++b)
            zz += ws[OFF_ZP + (n * NFB + b) * RN + tid];
        sZ2[tid] = zz;
    }
    __syncthreads();
    // stage F = (sum of 8 partials) / Z
    for (int idx = tid; idx < RN * 32; idx += 256) {
        float s = 0.f;
#pragma unroll
        for (int b = 0; b < NFB; ++b)
            s += ws[OFF_FP + ((size_t)(n * NFB + b)) * (RN * 32) + idx];
        sF[idx] = s / sZ2[idx >> 5];
    }
    if (tid < RN) {
        const float pmin = sstat[0], pmax = sstat[1];
        const float q1 = fmaf(Wq[0], pmin, bq[0]);
        const float q2 = fmaf(Wq[0], pmax, bq[0]);
        const float qlo = fminf(q1, q2), qhi = fmaxf(q1, q2);
        const float mid  = 0.5f * (qlo + qhi);
        const float half = fmaxf(0.5f * (qhi - qlo), 1e-6f);
        stn[tid] = fmaf(half, cosf(PI_F * (float)tid / (float)(RN - 1)), mid);
    }
    __syncthreads();

    const int il = tid >> 3;                 // 32 i's per block
    const int dg = tid & 7;                  // 4-wide d group
    const int i  = blockIdx.x * 32 + il;
    const float t = fmaf(Wq[0], ws[OFF_POOL + n * HW + i], bq[0]);  // q_i

    // Barycentric Lagrange, Chebyshev-2 weights (-1)^r * (1/2 at ends).
    float n0 = 0.f, n1 = 0.f, n2 = 0.f, n3 = 0.f, den = 0.f;
    float sgn = 1.0f;
#pragma unroll 8
    for (int r = 0; r < RN; ++r) {
        float d = t - stn[r];
        if (fabsf(d) < 1e-20f) d = 1e-20f;   // node-hit guard
        const float lam = (r == 0 || r == RN - 1) ? 0.5f : 1.0f;
        const float w = sgn * lam * frcp(d);
        sgn = -sgn;
        den += w;
        const float4 f4 = *(const float4*)(&sF[r * 32 + dg * 4]);
        n0 = fmaf(w, f4.x, n0);
        n1 = fmaf(w, f4.y, n1);
        n2 = fmaf(w, f4.z, n2);
        n3 = fmaf(w, f4.w, n3);
    }
    const float invden = frcp(den);
    const float g = gamma[0];
    const int c_out = i / 72;
    const int p_out = (i - c_out * 72) * 32 + dg * 4;
    const size_t base = (size_t)n * (CC * HW) + (size_t)c_out * HW + p_out;
    const float4 xv = *(const float4*)(x + base);
    float4 o;
    o.x = fmaf(g, n0 * invden, xv.x);
    o.y = fmaf(g, n1 * invden, xv.y);
    o.z = fmaf(g, n2 * invden, xv.z);
    o.w = fmaf(g, n3 * invden, xv.w);
    *(float4*)(out + base) = o;
}

extern "C" void kernel_launch(void* const* d_in, const int* in_sizes, int n_in,
                              void* d_out, int out_size, void* d_ws, size_t ws_size,
                              hipStream_t stream) {
    const float* x     = (const float*)d_in[0];
    const float* Wq    = (const float*)d_in[1];
    const float* bq    = (const float*)d_in[2];
    const float* Wk    = (const float*)d_in[3];
    const float* bk    = (const float*)d_in[4];
    const float* Wv    = (const float*)d_in[5];
    const float* bv    = (const float*)d_in[6];
    const float* gamma = (const float*)d_in[7];
    float* out = (float*)d_out;
    float* ws  = (float*)d_ws;   // needs only 2.4 MB

    // v is staged in d_out (overwritten by eval with the final result).
    prep_kernel<<<dim3(NPB, NB), 256, 0, stream>>>(x, Wv, bv, out, ws);
    fnode_kernel<<<dim3(NFB, NB), 1024, 0, stream>>>(Wq, bq, Wk, bk, out, ws);
    eval_kernel<<<dim3(72, NB), 256, 0, stream>>>(x, Wq, bq, gamma, ws, out);
}

// Round 14
// 105.784 us; speedup vs baseline: 1.4899x; 1.1549x over previous
//
#include <hip/hip_runtime.h>

// Shapes: x [n=32, c=32, s=1, h=48, w=48]; hw = 2304; c*s = 32.
// energy = q k^T is rank-1  =>  out[n,i,:] = gamma * f(q_i) + x, where
// f_d(t) = sum_j e^{t k_j} v_r[j,d] / sum_j e^{t k_j}.
// f is smooth in 1 variable -> RN-node Chebyshev barycentric interpolation
// on the exact per-batch q-range. v (9.4 MB) staged in d_out.
//
// R11 post-mortem: all top-5 dispatches are harness 268MB poison fills
// (~44us each); our kernels < 43us each. This round: RN 64->32 (error
// still ~1e-6*|v|, threshold 9.9e-2) halves fnode/eval VALU + F traffic.
#define NB 32
#define CC 32
#define HW 2304
#define RN 32                     // Chebyshev nodes per batch
#define PCHUNK 64                 // positions per prep block
#define NPB 36                    // prep blocks per batch  (HW/PCHUNK)
#define JCHUNK 288                // j rows per fnode block
#define NFB 8                     // fnode blocks per batch (HW/JCHUNK)
#define LOG2E 1.4426950408889634f
#define PI_F  3.14159265358979323846f

// Workspace layout (float offsets). Total = 346368 floats = 1.39 MB.
#define OFF_POOL 0u          // pool[n][hw]              73728
#define OFF_PART 73728u      // min/max partials         1152*2 = 2304
#define OFF_FP   76032u      // F partials [n][blk][r*32+d]  32*8*1024 = 262144
#define OFF_ZP   338176u     // Z partials [n][blk][r]       32*8*32   = 8192

__device__ __forceinline__ float frcp(float v) { return __builtin_amdgcn_rcpf(v); }

// ---------------------------------------------------------------------------
// Kernel 1: pool = mean_c + max_c (store); v = Wv@x + bv (1x1 conv) -> vout;
// per-block pool min/max partials.
// grid (36, 32), block 256: 64 positions/block, 4 threads per position
// (each computes 8 output channels). x tile + Wv^T staged in LDS.
// ---------------------------------------------------------------------------
__global__ __launch_bounds__(256) void prep_kernel(
    const float* __restrict__ x,
    const float* __restrict__ Wv, const float* __restrict__ bv,
    float* __restrict__ vout,      // = d_out used as scratch for v[n][c][hw]
    float* __restrict__ ws)
{
    __shared__ float sx[CC][PCHUNK];        // 8 KB   x tile, c-major
    __shared__ __align__(16) float sWvT[CC][36];  // transposed Wv, padded rows
    __shared__ float sbv[CC];
    const int tid = threadIdx.x;
    const int n   = blockIdx.y;
    const int pb  = blockIdx.x * PCHUNK;

    if (tid < CC) sbv[tid] = bv[tid];
    for (int idx = tid; idx < CC * CC; idx += 256) {
        const int o = idx >> 5, c = idx & 31;
        sWvT[c][o] = Wv[idx];               // Wv row-major [o][c]
    }
    const float* xb = x + (size_t)n * (CC * HW) + pb;
    for (int idx = tid; idx < CC * PCHUNK; idx += 256) {
        const int c = idx >> 6, p = idx & 63;
        sx[c][p] = xb[(size_t)c * HW + p];  // coalesced 256B per wave
    }
    __syncthreads();

    const int pos = tid & 63;
    const int og  = tid >> 6;               // 0..3 -> 8 output channels each

    float acc[8];
#pragma unroll
    for (int oo = 0; oo < 8; ++oo) acc[oo] = sbv[og * 8 + oo];
#pragma unroll
    for (int c = 0; c < CC; ++c) {
        const float xv = sx[c][pos];        // 2 lanes/bank, conflict-free
        const float4 w0 = *(const float4*)&sWvT[c][og * 8];      // broadcast
        const float4 w1 = *(const float4*)&sWvT[c][og * 8 + 4];  // broadcast
        acc[0] = fmaf(w0.x, xv, acc[0]); acc[1] = fmaf(w0.y, xv, acc[1]);
        acc[2] = fmaf(w0.z, xv, acc[2]); acc[3] = fmaf(w0.w, xv, acc[3]);
        acc[4] = fmaf(w1.x, xv, acc[4]); acc[5] = fmaf(w1.y, xv, acc[5]);
        acc[6] = fmaf(w1.z, xv, acc[6]); acc[7] = fmaf(w1.w, xv, acc[7]);
    }
    float* vb = vout + (size_t)n * (CC * HW) + pb + pos;
#pragma unroll
    for (int oo = 0; oo < 8; ++oo)
        vb[(size_t)(og * 8 + oo) * HW] = acc[oo];   // coalesced 256B per wave

    // pooling: wave 0 (og==0), one thread per position
    if (og == 0) {
        float sum = 0.f, mx = -3.0e38f;
#pragma unroll
        for (int c = 0; c < CC; ++c) {
            const float v = sx[c][pos];
            sum += v;
            mx = fmaxf(mx, v);
        }
        const float pool = sum * (1.0f / CC) + mx;
        ws[OFF_POOL + n * HW + pb + pos] = pool;
        float mn = pool, mxp = pool;
#pragma unroll
        for (int off = 32; off > 0; off >>= 1) {
            mn  = fminf(mn,  __shfl_xor(mn,  off));
            mxp = fmaxf(mxp, __shfl_xor(mxp, off));
        }
        if (tid == 0) {
            const int b = n * NPB + blockIdx.x;
            ws[OFF_PART + 2 * b]     = mn;
            ws[OFF_PART + 2 * b + 1] = mxp;
        }
    }
}

// ---------------------------------------------------------------------------
// Kernel 2: per-block PARTIAL F/Z (no atomics):
//   FP[n][blk][r][d] = sum_{j in chunk} e^{t_r k_j - m_r} v_r[j,d]
//   ZP[n][blk][r]    = sum_{j in chunk} e^{t_r k_j - m_r}
// grid (8, 32) = 256 blocks, block 1024 (16 waves).
// thread = (r = tid&31, dblk = (tid>>5)&3, jh = tid>>7): 36-iter j loop,
// 8-way jh partials merged via LDS (sv reused, pad-9), coalesced stores.
// ---------------------------------------------------------------------------
__global__ __launch_bounds__(1024) void fnode_kernel(
    const float* __restrict__ Wq, const float* __restrict__ bq,
    const float* __restrict__ Wk, const float* __restrict__ bk,
    const float* __restrict__ vscratch,
    float* __restrict__ ws)
{
    __shared__ __align__(16) float sv[JCHUNK * 32];   // 9216 floats = 36 KB
    __shared__ float sk[JCHUNK];
    __shared__ float sz[1024];
    const int tid = threadIdx.x;
    const int n   = blockIdx.y;
    const int bx  = blockIdx.x;
    const int jb  = bx * JCHUNK;

    // stage v slice (contiguous: v_r[j][d] == vflat[j*32+d]) and k chunk
    const float* vsrc = vscratch + (size_t)n * (CC * HW) + (size_t)jb * 32;
    for (int idx = tid; idx < JCHUNK * 32; idx += 1024)
        sv[idx] = vsrc[idx];
    const float Wk0 = Wk[0], bk0 = bk[0];
    for (int idx = tid; idx < JCHUNK; idx += 1024)
        sk[idx] = fmaf(Wk0, ws[OFF_POOL + n * HW + jb + idx], bk0);

    const int r    = tid & 31;
    const int dblk = (tid >> 5) & 3;
    const int jh   = tid >> 7;            // 0..7, 36 j's each
    float pmin = 3.0e38f, pmax = -3.0e38f;
    for (int b = 0; b < NPB; ++b) {       // uniform -> s_loads
        pmin = fminf(pmin, ws[OFF_PART + 2 * (n * NPB + b)]);
        pmax = fmaxf(pmax, ws[OFF_PART + 2 * (n * NPB + b) + 1]);
    }
    const float q1 = fmaf(Wq[0], pmin, bq[0]);
    const float q2 = fmaf(Wq[0], pmax, bq[0]);
    const float qlo = fminf(q1, q2), qhi = fmaxf(q1, q2);
    const float k1 = fmaf(Wk0, pmin, bk0);
    const float k2 = fmaf(Wk0, pmax, bk0);
    const float klo = fminf(k1, k2), khi = fmaxf(k1, k2);
    const float mid  = 0.5f * (qlo + qhi);
    const float half = fmaxf(0.5f * (qhi - qlo), 1e-6f);
    const float t  = fmaf(half, cosf(PI_F * (float)r / (float)(RN - 1)), mid);
    const float m  = fmaxf(t * klo, t * khi);   // == max_j t*k_j (k range exact)
    const float tl = t * LOG2E;
    const float ml = m * LOG2E;

    __syncthreads();

    float a0 = 0.f, a1 = 0.f, a2 = 0.f, a3 = 0.f;
    float a4 = 0.f, a5 = 0.f, a6 = 0.f, a7 = 0.f, az = 0.f;
    const float* svd = sv + dblk * 8;
    const int j0 = jh * 36;
#pragma unroll 4
    for (int jj = j0; jj < j0 + 36; ++jj) {
        const float e = exp2f(fmaf(tl, sk[jj], -ml));   // exponent <= 0
        const float4 va = *(const float4*)(svd + jj * 32);       // broadcast
        const float4 vb = *(const float4*)(svd + jj * 32 + 4);   // broadcast
        a0 = fmaf(e, va.x, a0); a1 = fmaf(e, va.y, a1);
        a2 = fmaf(e, va.z, a2); a3 = fmaf(e, va.w, a3);
        a4 = fmaf(e, vb.x, a4); a5 = fmaf(e, vb.y, a5);
        a6 = fmaf(e, vb.z, a6); a7 = fmaf(e, vb.w, a7);
        az += e;
    }

    __syncthreads();                // sv no longer needed as v; reuse for reduce
    // partial store: sred[jh][lid][9-pad], lid = dblk*32 + r = tid&127
    const int lid = tid & 127;
    float* sred = sv;               // 8 * 128 * 9 = 9216 floats = exactly sv
    {
        float* dst = sred + (jh * 128 + lid) * 9;
        dst[0] = a0; dst[1] = a1; dst[2] = a2; dst[3] = a3;
        dst[4] = a4; dst[5] = a5; dst[6] = a6; dst[7] = a7;
    }
    sz[tid] = az;
    __syncthreads();
    if (tid < 128) {
        // remapped so stores are contiguous: thread -> (rr = tid>>2, db = tid&3)
        const int rr = tid >> 2, db = tid & 3;
        float s[8];
#pragma unroll
        for (int dd = 0; dd < 8; ++dd) {
            float acc = 0.f;
#pragma unroll
            for (int h = 0; h < 8; ++h)
                acc += sred[(h * 128 + db * 32 + rr) * 9 + dd];
            s[dd] = acc;
        }
        // FP addr = (n*NFB+bx)*1024 + rr*32 + db*8 = base + tid*8 (contiguous)
        float* Fb = ws + OFF_FP + ((size_t)(n * NFB + bx)) * (RN * 32) + tid * 8;
        *(float4*)(Fb)     = make_float4(s[0], s[1], s[2], s[3]);
        *(float4*)(Fb + 4) = make_float4(s[4], s[5], s[6], s[7]);
        if (db == 0) {
            float z = 0.f;
#pragma unroll
            for (int h = 0; h < 8; ++h) z += sz[h * 128 + rr];
            ws[OFF_ZP + (n * NFB + bx) * RN + rr] = z;
        }
    }
}

// ---------------------------------------------------------------------------
// Kernel 3: sum the 8 F/Z partials while staging, then barycentric evaluation
// at each q_i + residual epilogue. Overwrites ALL of d_out (held v scratch).
// grid (72, 32), block 256: 8 threads per i (4 d's each) -> coalesced IO.
// ---------------------------------------------------------------------------
__global__ __launch_bounds__(256) void eval_kernel(
    const float* __restrict__ x,
    const float* __restrict__ Wq, const float* __restrict__ bq,
    const float* __restrict__ gamma,
    const float* __restrict__ ws,
    float* __restrict__ out)
{
    __shared__ __align__(16) float sF[RN * 32];
    __shared__ float stn[RN];
    __shared__ float sZ2[RN];
    __shared__ float sstat[2];
    const int tid = threadIdx.x;
    const int n   = blockIdx.y;

    if (tid == 0) {
        float pmin = 3.0e38f, pmax = -3.0e38f;
        for (int b = 0; b < NPB; ++b) {
            pmin = fminf(pmin, ws[OFF_PART + 2 * (n * NPB + b)]);
            pmax = fmaxf(pmax, ws[OFF_PART + 2 * (n * NPB + b) + 1]);
        }
        sstat[0] = pmin; sstat[1] = pmax;
    }
    if (tid < RN) {   // Z = sum of 8 partials
        float zz = 0.f;
#pragma unroll
        for (int b = 0; b < NFB; ++b)
            zz += ws[OFF_ZP + (n * NFB + b) * RN + tid];
        sZ2[tid] = zz;
    }
    __syncthreads();
    // stage F = (sum of 8 partials) / Z   (RN*32 = 1024 -> 4 iters)
    for (int idx = tid; idx < RN * 32; idx += 256) {
        float s = 0.f;
#pragma unroll
        for (int b = 0; b < NFB; ++b)
            s += ws[OFF_FP + ((size_t)(n * NFB + b)) * (RN * 32) + idx];
        sF[idx] = s / sZ2[idx >> 5];
    }
    if (tid < RN) {
        const float pmin = sstat[0], pmax = sstat[1];
        const float q1 = fmaf(Wq[0], pmin, bq[0]);
        const float q2 = fmaf(Wq[0], pmax, bq[0]);
        const float qlo = fminf(q1, q2), qhi = fmaxf(q1, q2);
        const float mid  = 0.5f * (qlo + qhi);
        const float half = fmaxf(0.5f * (qhi - qlo), 1e-6f);
        stn[tid] = fmaf(half, cosf(PI_F * (float)tid / (float)(RN - 1)), mid);
    }
    __syncthreads();

    const int il = tid >> 3;                 // 32 i's per block
    const int dg = tid & 7;                  // 4-wide d group
    const int i  = blockIdx.x * 32 + il;
    const float t = fmaf(Wq[0], ws[OFF_POOL + n * HW + i], bq[0]);  // q_i

    // Barycentric Lagrange, Chebyshev-2 weights (-1)^r * (1/2 at ends).
    float n0 = 0.f, n1 = 0.f, n2 = 0.f, n3 = 0.f, den = 0.f;
    float sgn = 1.0f;
#pragma unroll 8
    for (int r = 0; r < RN; ++r) {
        float d = t - stn[r];
        if (fabsf(d) < 1e-20f) d = 1e-20f;   // node-hit guard
        const float lam = (r == 0 || r == RN - 1) ? 0.5f : 1.0f;
        const float w = sgn * lam * frcp(d);
        sgn = -sgn;
        den += w;
        const float4 f4 = *(const float4*)(&sF[r * 32 + dg * 4]);
        n0 = fmaf(w, f4.x, n0);
        n1 = fmaf(w, f4.y, n1);
        n2 = fmaf(w, f4.z, n2);
        n3 = fmaf(w, f4.w, n3);
    }
    const float invden = frcp(den);
    const float g = gamma[0];
    const int c_out = i / 72;
    const int p_out = (i - c_out * 72) * 32 + dg * 4;
    const size_t base = (size_t)n * (CC * HW) + (size_t)c_out * HW + p_out;
    const float4 xv = *(const float4*)(x + base);
    float4 o;
    o.x = fmaf(g, n0 * invden, xv.x);
    o.y = fmaf(g, n1 * invden, xv.y);
    o.z = fmaf(g, n2 * invden, xv.z);
    o.w = fmaf(g, n3 * invden, xv.w);
    *(float4*)(out + base) = o;
}

extern "C" void kernel_launch(void* const* d_in, const int* in_sizes, int n_in,
                              void* d_out, int out_size, void* d_ws, size_t ws_size,
                              hipStream_t stream) {
    const float* x     = (const float*)d_in[0];
    const float* Wq    = (const float*)d_in[1];
    const float* bq    = (const float*)d_in[2];
    const float* Wk    = (const float*)d_in[3];
    const float* bk    = (const float*)d_in[4];
    const float* Wv    = (const float*)d_in[5];
    const float* bv    = (const float*)d_in[6];
    const float* gamma = (const float*)d_in[7];
    float* out = (float*)d_out;
    float* ws  = (float*)d_ws;   // needs only 1.39 MB

    // v is staged in d_out (overwritten by eval with the final result).
    prep_kernel<<<dim3(NPB, NB), 256, 0, stream>>>(x, Wv, bv, out, ws);
    fnode_kernel<<<dim3(NFB, NB), 1024, 0, stream>>>(Wq, bq, Wk, bk, out, ws);
    eval_kernel<<<dim3(72, NB), 256, 0, stream>>>(x, Wq, bq, gamma, ws, out);
}